// Round 7
// baseline (133.368 us; speedup 1.0000x reference)
//
#include <hip/hip_runtime.h>

#define HH 512
#define WW 512
#define TX 64                 /* tile width  */
#define TY 32                 /* tile height */
#define HALO 5
#define LTY (TY + 2 * HALO)   /* 42 staged rows */
#define NCP 37                /* staged column-pairs (74 cols / 2) */
#define STRE 38               /* padded row stride per parity plane (float4) */
#define PI_F 3.14159265358979323846f

// ---- compile-time disk geometry (template-guaranteed unroll; R3/R4 lesson:
// optimizer-dependent unrolling left runtime indices -> scratch spills).
constexpr int dimin(int dj) {
    return (dj == 0 || dj == 10) ? 5 : (dj == 1 || dj == 9) ? 2 : (dj == 5) ? 0 : 1;
}
constexpr int dimax(int dj) { return 10 - dimin(dj); }
// sorted position of d2 among the 14 distinct values {0,1,2,4,5,8,9,10,13,16,17,18,20,25}
constexpr int spv(int d2) {
    return d2 == 0 ? 0 : d2 == 1 ? 1 : d2 == 2 ? 2 : d2 == 4 ? 3 : d2 == 5 ? 4 :
           d2 == 8 ? 5 : d2 == 9 ? 6 : d2 == 10 ? 7 : d2 == 13 ? 8 : d2 == 16 ? 9 :
           d2 == 17 ? 10 : d2 == 18 ? 11 : d2 == 20 ? 12 : 13;
}
// LDS column C (0..11, relative to the thread's x-pair) serves strip s=0 (dj=C)
// and strip s=1 (dj=C-1). Row-range of the union (read-gate):
constexpr int rlo(int C) {
    int lo = 100;
    if (C <= 10) { int v = dimin(C);     if (v < lo) lo = v; }
    if (C >= 1)  { int v = dimin(C - 1); if (v < lo) lo = v; }
    return lo;
}
constexpr int rhi(int C) {
    int hi = -100;
    if (C <= 10) { int v = dimax(C) + 3;     if (v > hi) hi = v; }
    if (C >= 1)  { int v = dimax(C - 1) + 3; if (v > hi) hi = v; }
    return hi;
}

// strip S (output x = 2*sx+S), pixel P (output row 4*sy+P) consumes source
// row K at di = K-P, column C at dj = C-S.
template <int C, int K, int S, int P>
__device__ __forceinline__ void pstep(const float4& v, int rk, float (&acc)[2][4][4]) {
    constexpr int dj = C - S;
    if constexpr (dj >= 0 && dj <= 10) {
        constexpr int di = K - P;
        if constexpr (di >= dimin(dj) && di <= dimax(dj)) {
            constexpr int d2 = (di - 5) * (di - 5) + (dj - 5) * (dj - 5);
            const float wm = (rk > spv(d2)) ? 1.0f : 0.0f; // rank>s <=> r>=dist[s], exact
            acc[S][P][0] = fmaf(wm, v.x, acc[S][P][0]);
            acc[S][P][1] = fmaf(wm, v.y, acc[S][P][1]);
            acc[S][P][2] = fmaf(wm, v.z, acc[S][P][2]);
            acc[S][P][3] = fmaf(wm, v.w, acc[S][P][3]);
        }
    }
}

// one ds_read_b128 (compile-time offset) shared by up to 8 output pixels.
template <int C, int K>
__device__ __forceinline__ void kstep(const float4* __restrict__ eb,
                                      const float4* __restrict__ ob,
                                      float (&acc)[2][4][4]) {
    if constexpr (K >= rlo(C) && K <= rhi(C)) {
        const float4 v = (C & 1) ? ob[K * STRE + (C - 1) / 2] : eb[K * STRE + C / 2];
        const int rk = (int)(__float_as_uint(v.w) & 15u);
        pstep<C, K, 0, 0>(v, rk, acc); pstep<C, K, 0, 1>(v, rk, acc);
        pstep<C, K, 0, 2>(v, rk, acc); pstep<C, K, 0, 3>(v, rk, acc);
        pstep<C, K, 1, 0>(v, rk, acc); pstep<C, K, 1, 1>(v, rk, acc);
        pstep<C, K, 1, 2>(v, rk, acc); pstep<C, K, 1, 3>(v, rk, acc);
    }
}

template <int C>
__device__ __forceinline__ void colstep(const float4* __restrict__ eb,
                                        const float4* __restrict__ ob,
                                        float (&acc)[2][4][4]) {
    kstep<C, 0>(eb, ob, acc);  kstep<C, 1>(eb, ob, acc);  kstep<C, 2>(eb, ob, acc);
    kstep<C, 3>(eb, ob, acc);  kstep<C, 4>(eb, ob, acc);  kstep<C, 5>(eb, ob, acc);
    kstep<C, 6>(eb, ob, acc);  kstep<C, 7>(eb, ob, acc);  kstep<C, 8>(eb, ob, acc);
    kstep<C, 9>(eb, ob, acc);  kstep<C, 10>(eb, ob, acc); kstep<C, 11>(eb, ob, acc);
    kstep<C, 12>(eb, ob, acc); kstep<C, 13>(eb, ob, acc);
}

__device__ __forceinline__ float4 mkpix(const float* __restrict__ xb,
                                        const float (&dsort)[14], float le,
                                        int gy, int gx) {
    const int gi = gy * WW + gx;
    const float d = xb[3 * HH * WW + gi];
    const float r = fminf(fabsf(d) * le, (float)HALO);
    const float g = 1.0f / (PI_F * r * r + 1.0f);
    int rank = 0;
#pragma unroll
    for (int k = 0; k < 14; ++k) rank += (r >= dsort[k]) ? 1 : 0; // exact coverage
    // rank in [0,14] -> low 4 mantissa bits of g (rel. perturbation <= 2^-19)
    const float gm = __uint_as_float((__float_as_uint(g) & ~15u) | (unsigned)rank);
    return make_float4(xb[gi] * g, xb[HH * WW + gi] * g, xb[2 * HH * WW + gi] * g, gm);
}

// Depth-aware scatter (splat) bokeh as gather; 2x4 output block per thread.
// Horizontal sharing: the two strips' dj ranges overlap per LDS column ->
// 128 ds_read_b128 per 8 px (16/px vs 28.5/px in the 1x4 version).
__global__ __launch_bounds__(256, 2) void Scatter_Rendering_87101936763449_kernel(
    const float* __restrict__ x, const float* __restrict__ lens,
    const float* __restrict__ dk, float* __restrict__ out) {
    __shared__ float4 sgE[LTY * STRE]; // even staged columns (lane stride 16B)
    __shared__ float4 sgO[LTY * STRE]; // odd  staged columns

    const int b  = blockIdx.z;
    const int bx = blockIdx.x * TX;
    const int by = blockIdx.y * TY;
    const int t  = threadIdx.x;

    const float le = lens[b];
    const float* xb = x + (size_t)b * 4 * HH * WW;

    // 14 distinct dist values ascending, from the INPUT diskernel (exact floats
    // the reference compares with). Representative (a,c) per d2; static idx.
    float dsort[14];
    {
        constexpr int AA[14] = {0, 0, 1, 0, 1, 2, 0, 1, 2, 0, 1, 3, 2, 0};
        constexpr int CC[14] = {0, 1, 1, 2, 2, 2, 3, 3, 3, 4, 4, 3, 4, 5};
#pragma unroll
        for (int k = 0; k < 14; ++k) dsort[k] = dk[(5 + AA[k]) * 11 + (5 + CC[k])];
    }

    // Stage 42 rows x 37 column-pairs (74 cols), edge-clamped.
    for (int i = t; i < LTY * NCP; i += 256) {
        const int ly = i / NCP, c = i - ly * NCP;
        int gy = by + ly - HALO; gy = gy < 0 ? 0 : (gy > HH - 1 ? HH - 1 : gy);
        int ge = bx + 2 * c - HALO;     ge = ge < 0 ? 0 : (ge > WW - 1 ? WW - 1 : ge);
        int go = bx + 2 * c - HALO + 1; go = go < 0 ? 0 : (go > WW - 1 ? WW - 1 : go);
        sgE[ly * STRE + c] = mkpix(xb, dsort, le, gy, ge);
        sgO[ly * STRE + c] = mkpix(xb, dsort, le, gy, go);
    }

    __syncthreads();

    const int sx = t & 31;       // x-pair index (output x = bx + 2*sx + s)
    const int sy = t >> 5;       // quad-row (output y = by + 4*sy + p)
    const float4* eb = &sgE[(4 * sy) * STRE + sx];
    const float4* ob = &sgO[(4 * sy) * STRE + sx];

    float acc[2][4][4] = {{{0.f}}}; // [strip][p][{r,g,b,den}], all static idx

    colstep<0>(eb, ob, acc); colstep<1>(eb, ob, acc); colstep<2>(eb, ob, acc);
    colstep<3>(eb, ob, acc); colstep<4>(eb, ob, acc); colstep<5>(eb, ob, acc);
    colstep<6>(eb, ob, acc); colstep<7>(eb, ob, acc); colstep<8>(eb, ob, acc);
    colstep<9>(eb, ob, acc); colstep<10>(eb, ob, acc); colstep<11>(eb, ob, acc);

    // Coalesced float2 stores: adjacent x-pair per thread.
#pragma unroll
    for (int p = 0; p < 4; ++p) {
        const float inv0 = 1.0f / acc[0][p][3];
        const float inv1 = 1.0f / acc[1][p][3];
        const int y = by + 4 * sy + p;
#pragma unroll
        for (int ch = 0; ch < 3; ++ch) {
            float2 w = make_float2(acc[0][p][ch] * inv0, acc[1][p][ch] * inv1);
            *reinterpret_cast<float2*>(
                &out[((size_t)(b * 3 + ch) * HH + y) * WW + bx + 2 * sx]) = w;
        }
    }
}

extern "C" void kernel_launch(void* const* d_in, const int* in_sizes, int n_in,
                              void* d_out, int out_size, void* d_ws, size_t ws_size,
                              hipStream_t stream) {
    const float* x    = (const float*)d_in[0]; // (4,4,512,512)
    const float* lens = (const float*)d_in[1]; // (4,1)
    const float* dk   = (const float*)d_in[2]; // (11,11)
    float* out = (float*)d_out;                // (4,3,512,512)

    dim3 grid(WW / TX, HH / TY, 4);            // 8x16x4 = 512 blocks (2/CU)
    dim3 block(256);
    hipLaunchKernelGGL(Scatter_Rendering_87101936763449_kernel, grid, block, 0, stream,
                       x, lens, dk, out);
}

// Round 8
// 129.204 us; speedup vs baseline: 1.0322x; 1.0322x over previous
//
#include <hip/hip_runtime.h>

#define HH 512
#define WW 512
#define TX 64                 /* tile width  */
#define TY 32                 /* tile height */
#define HALO 5
#define LTY (TY + 2 * HALO)   /* 42 staged rows */
#define NCP 37                /* staged column-pairs (74 cols / 2) */
#define STRE 38               /* padded row stride per parity plane (float4) */
#define PI_F 3.14159265358979323846f

// ---- compile-time disk geometry (template-guaranteed unroll; R3/R4 lesson:
// optimizer-dependent unrolling left runtime indices -> scratch spills).
constexpr int dimin(int dj) {
    return (dj == 0 || dj == 10) ? 5 : (dj == 1 || dj == 9) ? 2 : (dj == 5) ? 0 : 1;
}
constexpr int dimax(int dj) { return 10 - dimin(dj); }
// sorted position of d2 among the 14 distinct values {0,1,2,4,5,8,9,10,13,16,17,18,20,25}
constexpr int spv(int d2) {
    return d2 == 0 ? 0 : d2 == 1 ? 1 : d2 == 2 ? 2 : d2 == 4 ? 3 : d2 == 5 ? 4 :
           d2 == 8 ? 5 : d2 == 9 ? 6 : d2 == 10 ? 7 : d2 == 13 ? 8 : d2 == 16 ? 9 :
           d2 == 17 ? 10 : d2 == 18 ? 11 : d2 == 20 ? 12 : 13;
}
// LDS column C (0..11, relative to the thread's x-pair) serves strip s=0 (dj=C)
// and strip s=1 (dj=C-1). Row-range of the union (read-gate):
constexpr int rlo(int C) {
    int lo = 100;
    if (C <= 10) { int v = dimin(C);     if (v < lo) lo = v; }
    if (C >= 1)  { int v = dimin(C - 1); if (v < lo) lo = v; }
    return lo;
}
constexpr int rhi(int C) {
    int hi = -100;
    if (C <= 10) { int v = dimax(C) + 3;     if (v > hi) hi = v; }
    if (C >= 1)  { int v = dimax(C - 1) + 3; if (v > hi) hi = v; }
    return hi;
}

// strip S (output x = 2*sx+S), pixel P (output row 4*sy+P) consumes source
// row K at di = K-P, column C at dj = C-S.
template <int C, int K, int S, int P>
__device__ __forceinline__ void pstep(const float4& v, int rk, float (&acc)[2][4][4]) {
    constexpr int dj = C - S;
    if constexpr (dj >= 0 && dj <= 10) {
        constexpr int di = K - P;
        if constexpr (di >= dimin(dj) && di <= dimax(dj)) {
            constexpr int d2 = (di - 5) * (di - 5) + (dj - 5) * (dj - 5);
            const float wm = (rk > spv(d2)) ? 1.0f : 0.0f; // rank>s <=> r>=dist[s], exact
            acc[S][P][0] = fmaf(wm, v.x, acc[S][P][0]);
            acc[S][P][1] = fmaf(wm, v.y, acc[S][P][1]);
            acc[S][P][2] = fmaf(wm, v.z, acc[S][P][2]);
            acc[S][P][3] = fmaf(wm, v.w, acc[S][P][3]);
        }
    }
}

// one ds_read_b128 (compile-time offset) shared by up to 8 output pixels.
template <int C, int K>
__device__ __forceinline__ void kstep(const float4* __restrict__ eb,
                                      const float4* __restrict__ ob,
                                      float (&acc)[2][4][4]) {
    if constexpr (K >= rlo(C) && K <= rhi(C)) {
        const float4 v = (C & 1) ? ob[K * STRE + (C - 1) / 2] : eb[K * STRE + C / 2];
        const int rk = (int)(__float_as_uint(v.w) & 15u);
        pstep<C, K, 0, 0>(v, rk, acc); pstep<C, K, 0, 1>(v, rk, acc);
        pstep<C, K, 0, 2>(v, rk, acc); pstep<C, K, 0, 3>(v, rk, acc);
        pstep<C, K, 1, 0>(v, rk, acc); pstep<C, K, 1, 1>(v, rk, acc);
        pstep<C, K, 1, 2>(v, rk, acc); pstep<C, K, 1, 3>(v, rk, acc);
    }
}

template <int C>
__device__ __forceinline__ void colstep(const float4* __restrict__ eb,
                                        const float4* __restrict__ ob,
                                        float (&acc)[2][4][4]) {
    kstep<C, 0>(eb, ob, acc);  kstep<C, 1>(eb, ob, acc);  kstep<C, 2>(eb, ob, acc);
    kstep<C, 3>(eb, ob, acc);  kstep<C, 4>(eb, ob, acc);  kstep<C, 5>(eb, ob, acc);
    kstep<C, 6>(eb, ob, acc);  kstep<C, 7>(eb, ob, acc);  kstep<C, 8>(eb, ob, acc);
    kstep<C, 9>(eb, ob, acc);  kstep<C, 10>(eb, ob, acc); kstep<C, 11>(eb, ob, acc);
    kstep<C, 12>(eb, ob, acc); kstep<C, 13>(eb, ob, acc);
}

__device__ __forceinline__ float4 mkpix(const float* __restrict__ xb,
                                        const float (&dsort)[14], float le,
                                        int gy, int gx) {
    const int gi = gy * WW + gx;
    const float d = xb[3 * HH * WW + gi];
    const float r = fminf(fabsf(d) * le, (float)HALO);
    const float g = 1.0f / (PI_F * r * r + 1.0f);
    int rank = 0;
#pragma unroll
    for (int k = 0; k < 14; ++k) rank += (r >= dsort[k]) ? 1 : 0; // exact coverage
    // rank in [0,14] -> low 4 mantissa bits of g (rel. perturbation <= 2^-19)
    const float gm = __uint_as_float((__float_as_uint(g) & ~15u) | (unsigned)rank);
    return make_float4(xb[gi] * g, xb[HH * WW + gi] * g, xb[2 * HH * WW + gi] * g, gm);
}

// Depth-aware scatter (splat) bokeh as gather; 2x4 output block per thread.
// Horizontal sharing: 128 ds_read_b128 per 8 px (16/px).
// R7 lesson: launch_bounds(256,2) let the backend TARGET 4 waves/EU (128 VGPR)
// and spill 250MB/launch of scratch (FETCH 101MB/WRITE 181MB, ~4.1TB/s = the
// whole runtime). amdgpu_waves_per_eu(2,2) pins the allocator's occupancy
// target at 2 waves/EU -> 256-VGPR budget -> no spill.
__global__ __launch_bounds__(256)
__attribute__((amdgpu_waves_per_eu(2, 2)))
void Scatter_Rendering_87101936763449_kernel(
    const float* __restrict__ x, const float* __restrict__ lens,
    const float* __restrict__ dk, float* __restrict__ out) {
    __shared__ float4 sgE[LTY * STRE]; // even staged columns (lane stride 16B)
    __shared__ float4 sgO[LTY * STRE]; // odd  staged columns

    const int b  = blockIdx.z;
    const int bx = blockIdx.x * TX;
    const int by = blockIdx.y * TY;
    const int t  = threadIdx.x;

    const float le = lens[b];
    const float* xb = x + (size_t)b * 4 * HH * WW;

    // 14 distinct dist values ascending, from the INPUT diskernel (exact floats
    // the reference compares with). Representative (a,c) per d2; static idx.
    float dsort[14];
    {
        constexpr int AA[14] = {0, 0, 1, 0, 1, 2, 0, 1, 2, 0, 1, 3, 2, 0};
        constexpr int CC[14] = {0, 1, 1, 2, 2, 2, 3, 3, 3, 4, 4, 3, 4, 5};
#pragma unroll
        for (int k = 0; k < 14; ++k) dsort[k] = dk[(5 + AA[k]) * 11 + (5 + CC[k])];
    }

    // Stage 42 rows x 37 column-pairs (74 cols), edge-clamped.
    for (int i = t; i < LTY * NCP; i += 256) {
        const int ly = i / NCP, c = i - ly * NCP;
        int gy = by + ly - HALO; gy = gy < 0 ? 0 : (gy > HH - 1 ? HH - 1 : gy);
        int ge = bx + 2 * c - HALO;     ge = ge < 0 ? 0 : (ge > WW - 1 ? WW - 1 : ge);
        int go = bx + 2 * c - HALO + 1; go = go < 0 ? 0 : (go > WW - 1 ? WW - 1 : go);
        sgE[ly * STRE + c] = mkpix(xb, dsort, le, gy, ge);
        sgO[ly * STRE + c] = mkpix(xb, dsort, le, gy, go);
    }

    __syncthreads();

    const int sx = t & 31;       // x-pair index (output x = bx + 2*sx + s)
    const int sy = t >> 5;       // quad-row (output y = by + 4*sy + p)
    const float4* eb = &sgE[(4 * sy) * STRE + sx];
    const float4* ob = &sgO[(4 * sy) * STRE + sx];

    float acc[2][4][4] = {{{0.f}}}; // [strip][p][{r,g,b,den}], all static idx

    colstep<0>(eb, ob, acc); colstep<1>(eb, ob, acc); colstep<2>(eb, ob, acc);
    colstep<3>(eb, ob, acc); colstep<4>(eb, ob, acc); colstep<5>(eb, ob, acc);
    colstep<6>(eb, ob, acc); colstep<7>(eb, ob, acc); colstep<8>(eb, ob, acc);
    colstep<9>(eb, ob, acc); colstep<10>(eb, ob, acc); colstep<11>(eb, ob, acc);

    // Coalesced float2 stores: adjacent x-pair per thread.
#pragma unroll
    for (int p = 0; p < 4; ++p) {
        const float inv0 = 1.0f / acc[0][p][3];
        const float inv1 = 1.0f / acc[1][p][3];
        const int y = by + 4 * sy + p;
#pragma unroll
        for (int ch = 0; ch < 3; ++ch) {
            float2 w = make_float2(acc[0][p][ch] * inv0, acc[1][p][ch] * inv1);
            *reinterpret_cast<float2*>(
                &out[((size_t)(b * 3 + ch) * HH + y) * WW + bx + 2 * sx]) = w;
        }
    }
}

extern "C" void kernel_launch(void* const* d_in, const int* in_sizes, int n_in,
                              void* d_out, int out_size, void* d_ws, size_t ws_size,
                              hipStream_t stream) {
    const float* x    = (const float*)d_in[0]; // (4,4,512,512)
    const float* lens = (const float*)d_in[1]; // (4,1)
    const float* dk   = (const float*)d_in[2]; // (11,11)
    float* out = (float*)d_out;                // (4,3,512,512)

    dim3 grid(WW / TX, HH / TY, 4);            // 8x16x4 = 512 blocks (2/CU)
    dim3 block(256);
    hipLaunchKernelGGL(Scatter_Rendering_87101936763449_kernel, grid, block, 0, stream,
                       x, lens, dk, out);
}

// Round 9
// 119.234 us; speedup vs baseline: 1.1185x; 1.0836x over previous
//
#include <hip/hip_runtime.h>

#define HH 512
#define WW 512
#define TX 64                 /* tile width  */
#define TY 32                 /* tile height */
#define HALO 5
#define LTY (TY + 2 * HALO)   /* 42 staged rows */
#define NCP 37                /* staged column-pairs (74 cols / 2) */
#define STRE 38               /* padded row stride per parity plane (float4) */
#define PI_F 3.14159265358979323846f

// ---- compile-time disk geometry (template-guaranteed unroll; R3/R4 lesson:
// optimizer-dependent unrolling left runtime indices -> scratch spills).
constexpr int dimin(int dj) {
    return (dj == 0 || dj == 10) ? 5 : (dj == 1 || dj == 9) ? 2 : (dj == 5) ? 0 : 1;
}
constexpr int dimax(int dj) { return 10 - dimin(dj); }
// sorted position of d2 among the 14 distinct values {0,1,2,4,5,8,9,10,13,16,17,18,20,25}
constexpr int spv(int d2) {
    return d2 == 0 ? 0 : d2 == 1 ? 1 : d2 == 2 ? 2 : d2 == 4 ? 3 : d2 == 5 ? 4 :
           d2 == 8 ? 5 : d2 == 9 ? 6 : d2 == 10 ? 7 : d2 == 13 ? 8 : d2 == 16 ? 9 :
           d2 == 17 ? 10 : d2 == 18 ? 11 : d2 == 20 ? 12 : 13;
}
// LDS column C (0..11, relative to the thread's x-pair) serves strip s=0 (dj=C)
// and strip s=1 (dj=C-1). Row-range of the union (read-gate):
constexpr int rlo(int C) {
    int lo = 100;
    if (C <= 10) { int v = dimin(C);     if (v < lo) lo = v; }
    if (C >= 1)  { int v = dimin(C - 1); if (v < lo) lo = v; }
    return lo;
}
constexpr int rhi(int C) {
    int hi = -100;
    if (C <= 10) { int v = dimax(C) + 3;     if (v > hi) hi = v; }
    if (C >= 1)  { int v = dimax(C - 1) + 3; if (v > hi) hi = v; }
    return hi;
}

// strip S (output x = 2*sx+S), pixel P (output row 4*sy+P) consumes source
// row K at di = K-P, column C at dj = C-S.
template <int C, int K, int S, int P>
__device__ __forceinline__ void pstep(const float4& v, int rk, float (&acc)[2][4][4]) {
    constexpr int dj = C - S;
    if constexpr (dj >= 0 && dj <= 10) {
        constexpr int di = K - P;
        if constexpr (di >= dimin(dj) && di <= dimax(dj)) {
            constexpr int d2 = (di - 5) * (di - 5) + (dj - 5) * (dj - 5);
            const float wm = (rk > spv(d2)) ? 1.0f : 0.0f; // rank>s <=> r>=dist[s], exact
            acc[S][P][0] = fmaf(wm, v.x, acc[S][P][0]);
            acc[S][P][1] = fmaf(wm, v.y, acc[S][P][1]);
            acc[S][P][2] = fmaf(wm, v.z, acc[S][P][2]);
            acc[S][P][3] = fmaf(wm, v.w, acc[S][P][3]);
        }
    }
}

// one ds_read_b128 (compile-time offset) shared by up to 8 output pixels.
template <int C, int K>
__device__ __forceinline__ void kstep(const float4* __restrict__ eb,
                                      const float4* __restrict__ ob,
                                      float (&acc)[2][4][4]) {
    if constexpr (K >= rlo(C) && K <= rhi(C)) {
        const float4 v = (C & 1) ? ob[K * STRE + (C - 1) / 2] : eb[K * STRE + C / 2];
        const int rk = (int)(__float_as_uint(v.w) & 15u);
        pstep<C, K, 0, 0>(v, rk, acc); pstep<C, K, 0, 1>(v, rk, acc);
        pstep<C, K, 0, 2>(v, rk, acc); pstep<C, K, 0, 3>(v, rk, acc);
        pstep<C, K, 1, 0>(v, rk, acc); pstep<C, K, 1, 1>(v, rk, acc);
        pstep<C, K, 1, 2>(v, rk, acc); pstep<C, K, 1, 3>(v, rk, acc);
    }
}

// R7/R8 lesson: with the body fully visible, the pre-RA scheduler hoists
// dozens of independent ds_reads (4 VGPR each) to hide latency, busts the
// 128-VGPR budget, and spills ~250MB/launch (FETCH 104MB/WRITE 185MB = the
// whole runtime). amdgpu_waves_per_eu was a no-op (R8: identical counters).
// Fix at the source-schedule level: sched_barrier(0) fences every half-column
// cap in-flight loads at ~7 (28 VGPR) -> fits; TLP (4 waves/SIMD) covers
// latency instead of intra-wave hoisting.
template <int C>
__device__ __forceinline__ void colstep(const float4* __restrict__ eb,
                                        const float4* __restrict__ ob,
                                        float (&acc)[2][4][4]) {
    kstep<C, 0>(eb, ob, acc);  kstep<C, 1>(eb, ob, acc);  kstep<C, 2>(eb, ob, acc);
    kstep<C, 3>(eb, ob, acc);  kstep<C, 4>(eb, ob, acc);  kstep<C, 5>(eb, ob, acc);
    kstep<C, 6>(eb, ob, acc);
    __builtin_amdgcn_sched_barrier(0);
    kstep<C, 7>(eb, ob, acc);  kstep<C, 8>(eb, ob, acc);  kstep<C, 9>(eb, ob, acc);
    kstep<C, 10>(eb, ob, acc); kstep<C, 11>(eb, ob, acc); kstep<C, 12>(eb, ob, acc);
    kstep<C, 13>(eb, ob, acc);
    __builtin_amdgcn_sched_barrier(0);
}

__device__ __forceinline__ float4 mkpix(const float* __restrict__ xb,
                                        const float (&dsort)[14], float le,
                                        int gy, int gx) {
    const int gi = gy * WW + gx;
    const float d = xb[3 * HH * WW + gi];
    const float r = fminf(fabsf(d) * le, (float)HALO);
    const float g = 1.0f / (PI_F * r * r + 1.0f);
    int rank = 0;
#pragma unroll
    for (int k = 0; k < 14; ++k) rank += (r >= dsort[k]) ? 1 : 0; // exact coverage
    // rank in [0,14] -> low 4 mantissa bits of g (rel. perturbation <= 2^-19)
    const float gm = __uint_as_float((__float_as_uint(g) & ~15u) | (unsigned)rank);
    return make_float4(xb[gi] * g, xb[HH * WW + gi] * g, xb[2 * HH * WW + gi] * g, gm);
}

// Depth-aware scatter (splat) bokeh as gather; 2x4 output block per thread.
// Horizontal sharing: 128 ds_read_b128 per 8 px (16/px vs 28.5 in 1x4).
__global__ __launch_bounds__(256)
void Scatter_Rendering_87101936763449_kernel(
    const float* __restrict__ x, const float* __restrict__ lens,
    const float* __restrict__ dk, float* __restrict__ out) {
    __shared__ float4 sgE[LTY * STRE]; // even staged columns (lane stride 16B)
    __shared__ float4 sgO[LTY * STRE]; // odd  staged columns

    const int b  = blockIdx.z;
    const int bx = blockIdx.x * TX;
    const int by = blockIdx.y * TY;
    const int t  = threadIdx.x;

    const float le = lens[b];
    const float* xb = x + (size_t)b * 4 * HH * WW;

    // 14 distinct dist values ascending, from the INPUT diskernel (exact floats
    // the reference compares with). Representative (a,c) per d2; static idx.
    float dsort[14];
    {
        constexpr int AA[14] = {0, 0, 1, 0, 1, 2, 0, 1, 2, 0, 1, 3, 2, 0};
        constexpr int CC[14] = {0, 1, 1, 2, 2, 2, 3, 3, 3, 4, 4, 3, 4, 5};
#pragma unroll
        for (int k = 0; k < 14; ++k) dsort[k] = dk[(5 + AA[k]) * 11 + (5 + CC[k])];
    }

    // Stage 42 rows x 37 column-pairs (74 cols), edge-clamped.
    for (int i = t; i < LTY * NCP; i += 256) {
        const int ly = i / NCP, c = i - ly * NCP;
        int gy = by + ly - HALO; gy = gy < 0 ? 0 : (gy > HH - 1 ? HH - 1 : gy);
        int ge = bx + 2 * c - HALO;     ge = ge < 0 ? 0 : (ge > WW - 1 ? WW - 1 : ge);
        int go = bx + 2 * c - HALO + 1; go = go < 0 ? 0 : (go > WW - 1 ? WW - 1 : go);
        sgE[ly * STRE + c] = mkpix(xb, dsort, le, gy, ge);
        sgO[ly * STRE + c] = mkpix(xb, dsort, le, gy, go);
    }

    __syncthreads();

    const int sx = t & 31;       // x-pair index (output x = bx + 2*sx + s)
    const int sy = t >> 5;       // quad-row (output y = by + 4*sy + p)
    const float4* eb = &sgE[(4 * sy) * STRE + sx];
    const float4* ob = &sgO[(4 * sy) * STRE + sx];

    float acc[2][4][4] = {{{0.f}}}; // [strip][p][{r,g,b,den}], all static idx

    colstep<0>(eb, ob, acc); colstep<1>(eb, ob, acc); colstep<2>(eb, ob, acc);
    colstep<3>(eb, ob, acc); colstep<4>(eb, ob, acc); colstep<5>(eb, ob, acc);
    colstep<6>(eb, ob, acc); colstep<7>(eb, ob, acc); colstep<8>(eb, ob, acc);
    colstep<9>(eb, ob, acc); colstep<10>(eb, ob, acc); colstep<11>(eb, ob, acc);

    // Coalesced float2 stores: adjacent x-pair per thread.
#pragma unroll
    for (int p = 0; p < 4; ++p) {
        const float inv0 = 1.0f / acc[0][p][3];
        const float inv1 = 1.0f / acc[1][p][3];
        const int y = by + 4 * sy + p;
#pragma unroll
        for (int ch = 0; ch < 3; ++ch) {
            float2 w = make_float2(acc[0][p][ch] * inv0, acc[1][p][ch] * inv1);
            *reinterpret_cast<float2*>(
                &out[((size_t)(b * 3 + ch) * HH + y) * WW + bx + 2 * sx]) = w;
        }
    }
}

extern "C" void kernel_launch(void* const* d_in, const int* in_sizes, int n_in,
                              void* d_out, int out_size, void* d_ws, size_t ws_size,
                              hipStream_t stream) {
    const float* x    = (const float*)d_in[0]; // (4,4,512,512)
    const float* lens = (const float*)d_in[1]; // (4,1)
    const float* dk   = (const float*)d_in[2]; // (11,11)
    float* out = (float*)d_out;                // (4,3,512,512)

    dim3 grid(WW / TX, HH / TY, 4);            // 8x16x4 = 512 blocks (2/CU)
    dim3 block(256);
    hipLaunchKernelGGL(Scatter_Rendering_87101936763449_kernel, grid, block, 0, stream,
                       x, lens, dk, out);
}

// Round 11
// 89.302 us; speedup vs baseline: 1.4935x; 1.3352x over previous
//
#include <hip/hip_runtime.h>
#include <hip/hip_fp16.h>

#define HH 512
#define WW 512
#define TILE 32
#define HALO 5
#define LT (TILE + 2 * HALO) /* 42 */
#define STR 43               /* LDS row stride in uint4 */
#define PI_F 3.14159265358979323846f

// ---- compile-time disk geometry (template-guaranteed unroll; R3/R4 lesson:
// optimizer-dependent unrolling left runtime indices -> scratch spills).
constexpr int dimin(int dj) {
    return (dj == 0 || dj == 10) ? 5 : (dj == 1 || dj == 9) ? 2 : (dj == 5) ? 0 : 1;
}
constexpr int dimax(int dj) { return 10 - dimin(dj); }
// sorted position of d2 among the 14 distinct values {0,1,2,4,5,8,9,10,13,16,17,18,20,25}
constexpr int spv(int d2) {
    return d2 == 0 ? 0 : d2 == 1 ? 1 : d2 == 2 ? 2 : d2 == 4 ? 3 : d2 == 5 ? 4 :
           d2 == 8 ? 5 : d2 == 9 ? 6 : d2 == 10 ? 7 : d2 == 13 ? 8 : d2 == 16 ? 9 :
           d2 == 17 ? 10 : d2 == 18 ? 11 : d2 == 20 ? 12 : 13;
}

// Payload per source pixel (16B, one ds_read_b128):
//   w.x = f16pair(s0, s1)   w.y = f16pair(s2, g)   w.z = rank   w.w = pad
// Accumulate num01 and (num2, den) as packed halves: per (px,offset) cost is
// cmp + cndmask(0x3C003C00 mask) + 2*v_pk_fma_f16 = 4 VALU (was 6 f32 ops).

// pixel P (output row yloc+P) consumes source row K at di = K-P, column DJ.
template <int DJ, int K, int P>
__device__ __forceinline__ void pstep(__half2 a01, __half2 a2g, unsigned rk,
                                      __half2 (&acc01)[4], __half2 (&acc2d)[4]) {
    constexpr int di = K - P;
    if constexpr (di >= dimin(DJ) && di <= dimax(DJ)) {
        constexpr int d2 = (di - 5) * (di - 5) + (DJ - 5) * (DJ - 5);
        // rank > s  <=>  r >= dsort[s] = dist(d2): exact coverage, as reference
        const unsigned wmu = (rk > (unsigned)spv(d2)) ? 0x3C003C00u : 0u; // (1,1)|(0,0) f16
        const __half2 wm = __builtin_bit_cast(__half2, wmu);
        acc01[P] = __hfma2(a01, wm, acc01[P]);
        acc2d[P] = __hfma2(a2g, wm, acc2d[P]);
    }
}

// one ds_read_b128 at compile-time offset, shared by a 1x4 output strip.
template <int DJ, int K>
__device__ __forceinline__ void kstep(const uint4* __restrict__ sgp,
                                      __half2 (&acc01)[4], __half2 (&acc2d)[4]) {
    if constexpr (K >= dimin(DJ) && K <= dimax(DJ) + 3) {
        const uint4 v = sgp[K * STR + DJ];
        const __half2 a01 = __builtin_bit_cast(__half2, v.x);
        const __half2 a2g = __builtin_bit_cast(__half2, v.y);
        const unsigned rk = v.z; // rank: no extraction needed (own word)
        pstep<DJ, K, 0>(a01, a2g, rk, acc01, acc2d);
        pstep<DJ, K, 1>(a01, a2g, rk, acc01, acc2d);
        pstep<DJ, K, 2>(a01, a2g, rk, acc01, acc2d);
        pstep<DJ, K, 3>(a01, a2g, rk, acc01, acc2d);
    }
}

template <int DJ>
__device__ __forceinline__ void colstep(const uint4* __restrict__ sgp,
                                        __half2 (&acc01)[4], __half2 (&acc2d)[4]) {
    kstep<DJ, 0>(sgp, acc01, acc2d);  kstep<DJ, 1>(sgp, acc01, acc2d);
    kstep<DJ, 2>(sgp, acc01, acc2d);  kstep<DJ, 3>(sgp, acc01, acc2d);
    kstep<DJ, 4>(sgp, acc01, acc2d);  kstep<DJ, 5>(sgp, acc01, acc2d);
    kstep<DJ, 6>(sgp, acc01, acc2d);  kstep<DJ, 7>(sgp, acc01, acc2d);
    kstep<DJ, 8>(sgp, acc01, acc2d);  kstep<DJ, 9>(sgp, acc01, acc2d);
    kstep<DJ, 10>(sgp, acc01, acc2d); kstep<DJ, 11>(sgp, acc01, acc2d);
    kstep<DJ, 12>(sgp, acc01, acc2d); kstep<DJ, 13>(sgp, acc01, acc2d);
}

// Depth-aware scatter (splat) bokeh as gather; 1x4 strip per thread (the R6
// structure: VGPR 64, zero spill, ~31us — reverted after 2x4 proved register-
// infeasible in R7/R8/R9). Single change vs R6: packed-f16 accumulation.
__global__ __launch_bounds__(256, 4) void Scatter_Rendering_87101936763449_kernel(
    const float* __restrict__ x, const float* __restrict__ lens,
    const float* __restrict__ dk, float* __restrict__ out) {
    __shared__ uint4 sg[LT * STR];

    const int b  = blockIdx.z;
    const int bx = blockIdx.x * TILE;
    const int by = blockIdx.y * TILE;
    const int t  = threadIdx.x;

    const float le = lens[b];
    const float* xb = x + (size_t)b * 4 * HH * WW;

    // 14 distinct dist values ascending, straight from the INPUT diskernel
    // (exact floats the reference compares with). Static indices -> registers.
    float dsort[14];
    {
        constexpr int AA[14] = {0, 0, 1, 0, 1, 2, 0, 1, 2, 0, 1, 3, 2, 0};
        constexpr int CC[14] = {0, 1, 1, 2, 2, 2, 3, 3, 3, 4, 4, 3, 4, 5};
#pragma unroll
        for (int k = 0; k < 14; ++k) dsort[k] = dk[(5 + AA[k]) * 11 + (5 + CC[k])];
    }

    // Stage 42x42 halo'd tile: one uint4 per source pixel.
    for (int i = t; i < LT * LT; i += 256) {
        int ly = i / LT, lx = i - ly * LT;
        int gy = by + ly - HALO; gy = gy < 0 ? 0 : (gy > HH - 1 ? HH - 1 : gy);
        int gx = bx + lx - HALO; gx = gx < 0 ? 0 : (gx > WW - 1 ? WW - 1 : gx);
        int gi = gy * WW + gx;
        float d = xb[3 * HH * WW + gi];
        float r = fminf(fabsf(d) * le, (float)HALO);
        float g = 1.0f / (PI_F * r * r + 1.0f);
        unsigned rank = 0;
#pragma unroll
        for (int k = 0; k < 14; ++k) rank += (r >= dsort[k]) ? 1u : 0u; // exact coverage
        const __half2 h01 = __floats2half2_rn(xb[gi] * g, xb[HH * WW + gi] * g);
        const __half2 h2g = __floats2half2_rn(xb[2 * HH * WW + gi] * g, g);
        sg[ly * STR + lx] = make_uint4(__builtin_bit_cast(unsigned, h01),
                                       __builtin_bit_cast(unsigned, h2g), rank, 0u);
    }

    __syncthreads();

    const int tx   = t & 31;
    const int yloc = (t >> 5) * 4; // this thread owns output rows yloc..yloc+3

    __half2 acc01[4], acc2d[4]; // packed (num0,num1) and (num2,den) per pixel
#pragma unroll
    for (int p = 0; p < 4; ++p) {
        acc01[p] = __float2half2_rn(0.0f);
        acc2d[p] = __float2half2_rn(0.0f);
    }

    const uint4* sgp = &sg[yloc * STR + tx]; // all further offsets compile-time

    colstep<0>(sgp, acc01, acc2d); colstep<1>(sgp, acc01, acc2d);
    colstep<2>(sgp, acc01, acc2d); colstep<3>(sgp, acc01, acc2d);
    colstep<4>(sgp, acc01, acc2d); colstep<5>(sgp, acc01, acc2d);
    colstep<6>(sgp, acc01, acc2d); colstep<7>(sgp, acc01, acc2d);
    colstep<8>(sgp, acc01, acc2d); colstep<9>(sgp, acc01, acc2d);
    colstep<10>(sgp, acc01, acc2d);

#pragma unroll
    for (int p = 0; p < 4; ++p) {
        const float n0  = __low2float(acc01[p]);
        const float n1  = __high2float(acc01[p]);
        const float n2  = __low2float(acc2d[p]);
        const float den = __high2float(acc2d[p]);
        const float inv = 1.0f / den;
        const size_t o = (size_t)b * 3 * HH * WW + (size_t)(by + yloc + p) * WW + (bx + tx);
        out[o]               = n0 * inv;
        out[o + HH * WW]     = n1 * inv;
        out[o + 2 * HH * WW] = n2 * inv;
    }
}

extern "C" void kernel_launch(void* const* d_in, const int* in_sizes, int n_in,
                              void* d_out, int out_size, void* d_ws, size_t ws_size,
                              hipStream_t stream) {
    const float* x    = (const float*)d_in[0]; // (4,4,512,512)
    const float* lens = (const float*)d_in[1]; // (4,1)
    const float* dk   = (const float*)d_in[2]; // (11,11)
    float* out = (float*)d_out;                // (4,3,512,512)

    dim3 grid(WW / TILE, HH / TILE, 4);        // 16x16x4 = 1024 blocks (4/CU)
    dim3 block(256);
    hipLaunchKernelGGL(Scatter_Rendering_87101936763449_kernel, grid, block, 0, stream,
                       x, lens, dk, out);
}

// Round 14
// 88.910 us; speedup vs baseline: 1.5000x; 1.0044x over previous
//
#include <hip/hip_runtime.h>
#include <hip/hip_fp16.h>

#define HH 512
#define WW 512
#define TXW 64                /* tile width  */
#define TYH 32                /* tile height */
#define HALO 5
#define LR (TYH + 2 * HALO)   /* 42 staged rows */
#define LC (TXW + 2 * HALO)   /* 74 staged cols */
#define STR 75                /* LDS row stride in uint4 (pad) */
#define PI_F 3.14159265358979323846f

// ---- compile-time disk geometry (template-guaranteed unroll; R3/R4 lesson).
constexpr int dimin(int dj) {
    return (dj == 0 || dj == 10) ? 5 : (dj == 1 || dj == 9) ? 2 : (dj == 5) ? 0 : 1;
}
constexpr int dimax(int dj) { return 10 - dimin(dj); }
// sorted position of d2 among the 14 distinct values {0,1,2,4,5,8,9,10,13,16,17,18,20,25}
constexpr int spv(int d2) {
    return d2 == 0 ? 0 : d2 == 1 ? 1 : d2 == 2 ? 2 : d2 == 4 ? 3 : d2 == 5 ? 4 :
           d2 == 8 ? 5 : d2 == 9 ? 6 : d2 == 10 ? 7 : d2 == 13 ? 8 : d2 == 16 ? 9 :
           d2 == 17 ? 10 : d2 == 18 ? 11 : d2 == 20 ? 12 : 13;
}

// Payload per source pixel (16B): x=f16(s0,s1) y=f16(s2,g) z=rank w=pad.
// R11 proved this exact payload at absmax 0.031 (threshold 0.099).

// pixel P (output row yloc+P) consumes source row K at di = K-P, column DJ.
template <int DJ, int K, int P>
__device__ __forceinline__ void pstep(__half2 a01, __half2 a2g, unsigned rk,
                                      __half2 (&acc01)[8], __half2 (&acc2d)[8]) {
    constexpr int di = K - P;
    if constexpr (di >= dimin(DJ) && di <= dimax(DJ)) {
        constexpr int d2 = (di - 5) * (di - 5) + (DJ - 5) * (DJ - 5);
        // rank > s  <=>  r >= dsort[s] = dist(d2): exact coverage, as reference
        const unsigned wmu = (rk > (unsigned)spv(d2)) ? 0x3C003C00u : 0u;
        const __half2 wm = __builtin_bit_cast(__half2, wmu);
        acc01[P] = __hfma2(a01, wm, acc01[P]);
        acc2d[P] = __hfma2(a2g, wm, acc2d[P]);
    }
}

// one ds_read_b128 at compile-time offset, shared by a 1x8 output strip.
template <int DJ, int K>
__device__ __forceinline__ void kstep(const uint4* __restrict__ sgp,
                                      __half2 (&acc01)[8], __half2 (&acc2d)[8]) {
    if constexpr (K >= dimin(DJ) && K <= dimax(DJ) + 7) {
        const uint4 v = sgp[K * STR + DJ];
        const __half2 a01 = __builtin_bit_cast(__half2, v.x);
        const __half2 a2g = __builtin_bit_cast(__half2, v.y);
        const unsigned rk = v.z;
        pstep<DJ, K, 0>(a01, a2g, rk, acc01, acc2d);
        pstep<DJ, K, 1>(a01, a2g, rk, acc01, acc2d);
        pstep<DJ, K, 2>(a01, a2g, rk, acc01, acc2d);
        pstep<DJ, K, 3>(a01, a2g, rk, acc01, acc2d);
        pstep<DJ, K, 4>(a01, a2g, rk, acc01, acc2d);
        pstep<DJ, K, 5>(a01, a2g, rk, acc01, acc2d);
        pstep<DJ, K, 6>(a01, a2g, rk, acc01, acc2d);
        pstep<DJ, K, 7>(a01, a2g, rk, acc01, acc2d);
    }
}

template <int DJ>
__device__ __forceinline__ void colstep(const uint4* __restrict__ sgp,
                                        __half2 (&acc01)[8], __half2 (&acc2d)[8]) {
    kstep<DJ, 0>(sgp, acc01, acc2d);  kstep<DJ, 1>(sgp, acc01, acc2d);
    kstep<DJ, 2>(sgp, acc01, acc2d);  kstep<DJ, 3>(sgp, acc01, acc2d);
    kstep<DJ, 4>(sgp, acc01, acc2d);  kstep<DJ, 5>(sgp, acc01, acc2d);
    kstep<DJ, 6>(sgp, acc01, acc2d);  kstep<DJ, 7>(sgp, acc01, acc2d);
    kstep<DJ, 8>(sgp, acc01, acc2d);  kstep<DJ, 9>(sgp, acc01, acc2d);
    kstep<DJ, 10>(sgp, acc01, acc2d); kstep<DJ, 11>(sgp, acc01, acc2d);
    kstep<DJ, 12>(sgp, acc01, acc2d); kstep<DJ, 13>(sgp, acc01, acc2d);
    kstep<DJ, 14>(sgp, acc01, acc2d); kstep<DJ, 15>(sgp, acc01, acc2d);
    kstep<DJ, 16>(sgp, acc01, acc2d); kstep<DJ, 17>(sgp, acc01, acc2d);
}

// Depth-aware scatter (splat) bokeh as gather; 1x8 strip per thread.
// R11 post-mortem: f16 VALU-halving was neutral -> latency-bound, not VALU.
// 1x8 cuts reads/px 28.5 -> 19.75 and doubles per-wave ILP; f16 keeps the
// 8-px accumulator at 16 VGPR (register-feasible, unlike the R7 2x4-f32).
// Wave = 64 consecutive sx -> every ds_read_b128 is 64 contiguous words
// (conflict-free). LDS 50.4KB caps 3 blocks/CU -> allocator never enters the
// 128-VGPR clamp regime that spilled R7.
__global__ __launch_bounds__(256) void Scatter_Rendering_87101936763449_kernel(
    const float* __restrict__ x, const float* __restrict__ lens,
    const float* __restrict__ dk, float* __restrict__ out) {
    __shared__ uint4 sg[LR * STR];

    const int b  = blockIdx.z;
    const int bx = blockIdx.x * TXW;
    const int by = blockIdx.y * TYH;
    const int t  = threadIdx.x;

    const float le = lens[b];
    const float* xb = x + (size_t)b * 4 * HH * WW;

    // 14 distinct dist values ascending, straight from the INPUT diskernel
    // (exact floats the reference compares with). Static indices -> registers.
    float dsort[14];
    {
        constexpr int AA[14] = {0, 0, 1, 0, 1, 2, 0, 1, 2, 0, 1, 3, 2, 0};
        constexpr int CC[14] = {0, 1, 1, 2, 2, 2, 3, 3, 3, 4, 4, 3, 4, 5};
#pragma unroll
        for (int k = 0; k < 14; ++k) dsort[k] = dk[(5 + AA[k]) * 11 + (5 + CC[k])];
    }

    // Stage 42x74 halo'd tile: one uint4 per source pixel.
    for (int i = t; i < LR * LC; i += 256) {
        int ly = i / LC, lx = i - ly * LC;
        int gy = by + ly - HALO; gy = gy < 0 ? 0 : (gy > HH - 1 ? HH - 1 : gy);
        int gx = bx + lx - HALO; gx = gx < 0 ? 0 : (gx > WW - 1 ? WW - 1 : gx);
        int gi = gy * WW + gx;
        float d = xb[3 * HH * WW + gi];
        float r = fminf(fabsf(d) * le, (float)HALO);
        float g = 1.0f / (PI_F * r * r + 1.0f);
        unsigned rank = 0;
#pragma unroll
        for (int k = 0; k < 14; ++k) rank += (r >= dsort[k]) ? 1u : 0u; // exact coverage
        const __half2 h01 = __floats2half2_rn(xb[gi] * g, xb[HH * WW + gi] * g);
        const __half2 h2g = __floats2half2_rn(xb[2 * HH * WW + gi] * g, g);
        sg[ly * STR + lx] = make_uint4(__builtin_bit_cast(unsigned, h01),
                                       __builtin_bit_cast(unsigned, h2g), rank, 0u);
    }

    __syncthreads();

    const int sx   = t & 63;       // column within tile (wave = 64 consecutive)
    const int yloc = (t >> 6) * 8; // this thread owns output rows yloc..yloc+7

    __half2 acc01[8], acc2d[8];
#pragma unroll
    for (int p = 0; p < 8; ++p) {
        acc01[p] = __float2half2_rn(0.0f);
        acc2d[p] = __float2half2_rn(0.0f);
    }

    const uint4* sgp = &sg[yloc * STR + sx]; // all further offsets compile-time

    colstep<0>(sgp, acc01, acc2d); colstep<1>(sgp, acc01, acc2d);
    colstep<2>(sgp, acc01, acc2d); colstep<3>(sgp, acc01, acc2d);
    colstep<4>(sgp, acc01, acc2d); colstep<5>(sgp, acc01, acc2d);
    colstep<6>(sgp, acc01, acc2d); colstep<7>(sgp, acc01, acc2d);
    colstep<8>(sgp, acc01, acc2d); colstep<9>(sgp, acc01, acc2d);
    colstep<10>(sgp, acc01, acc2d);

#pragma unroll
    for (int p = 0; p < 8; ++p) {
        const float n0  = __low2float(acc01[p]);
        const float n1  = __high2float(acc01[p]);
        const float n2  = __low2float(acc2d[p]);
        const float den = __high2float(acc2d[p]);
        const float inv = 1.0f / den;
        const size_t o = (size_t)b * 3 * HH * WW + (size_t)(by + yloc + p) * WW + (bx + sx);
        out[o]               = n0 * inv;
        out[o + HH * WW]     = n1 * inv;
        out[o + 2 * HH * WW] = n2 * inv;
    }
}

extern "C" void kernel_launch(void* const* d_in, const int* in_sizes, int n_in,
                              void* d_out, int out_size, void* d_ws, size_t ws_size,
                              hipStream_t stream) {
    const float* x    = (const float*)d_in[0]; // (4,4,512,512)
    const float* lens = (const float*)d_in[1]; // (4,1)
    const float* dk   = (const float*)d_in[2]; // (11,11)
    float* out = (float*)d_out;                // (4,3,512,512)

    dim3 grid(WW / TXW, HH / TYH, 4);          // 8x16x4 = 512 blocks (2/CU)
    dim3 block(256);
    hipLaunchKernelGGL(Scatter_Rendering_87101936763449_kernel, grid, block, 0, stream,
                       x, lens, dk, out);
}